// Round 1
// 728.697 us; speedup vs baseline: 1.0228x; 1.0228x over previous
//
#include <hip/hip_runtime.h>

typedef __bf16 bf16x8 __attribute__((ext_vector_type(8)));
typedef __bf16 bf16x4 __attribute__((ext_vector_type(4)));
typedef float f32x4 __attribute__((ext_vector_type(4)));

#define EMBED 584
#define KP 608      // K padded to 19*32 (zero-filled cols 584..607)
#define HEADS 8
#define HS 73
#define HSQ 80      // padded head size in q/k storage (16B-aligned rows)
#define CTX 200
#define NBATCH 256
#define MROWS 51200 // NBATCH*CTX
#define NQKV 1752   // 3*EMBED

// attention LDS geometry (halfword strides, all rows 16B-aligned)
#define CH 112      // keys per chunk (2 chunks cover 224 >= 200)
#define KSS 104     // Ks stride: 96 cols used + 8 pad (208 B rows)
#define VTS 136     // Vt stride: 128 cols used + 8 pad (272 B rows)
#define PSS 136     // Ps stride

// async global->LDS 16B copy: LDS dest is wave-uniform base + lane*16
__device__ __forceinline__ void gld_lds16(__bf16* lds, const __bf16* g) {
  __builtin_amdgcn_global_load_lds(
      (const __attribute__((address_space(1))) void*)g,
      (__attribute__((address_space(3))) void*)lds, 16, 0, 0);
}

// ---- fp32 -> bf16 convert x into padded [51200][608], 8 elems/thread ----
__global__ __launch_bounds__(256) void cvt_x(const float* __restrict__ x,
                                             __bf16* __restrict__ out) {
  int i = blockIdx.x * 256 + threadIdx.x;   // 15200*256 = 3,891,200 exact
  int r = i / 76, slot = i - r * 76;
  int col = slot * 8;
  bf16x8 o8 = {};
  if (col < EMBED) {
    const float4* s4 = (const float4*)(x + (size_t)r * EMBED + col);
    float4 f0 = s4[0], f1 = s4[1];
    o8[0] = (__bf16)f0.x; o8[1] = (__bf16)f0.y; o8[2] = (__bf16)f0.z; o8[3] = (__bf16)f0.w;
    o8[4] = (__bf16)f1.x; o8[5] = (__bf16)f1.y; o8[6] = (__bf16)f1.z; o8[7] = (__bf16)f1.w;
  }
  *(bf16x8*)(out + (size_t)r * KP + col) = o8;
}

// ---- pack Wq|Wk|Wv|Wo -> bf16 [2336][608] (zero pad cols) ----
__global__ __launch_bounds__(256) void pack_w(const float* __restrict__ Wq,
                                              const float* __restrict__ Wk,
                                              const float* __restrict__ Wv,
                                              const float* __restrict__ Wo,
                                              __bf16* __restrict__ out) {
  int i = blockIdx.x * 256 + threadIdx.x;
  if (i >= 2336 * 76) return;
  int r = i / 76, slot = i - r * 76;
  int col = slot * 8;
  bf16x8 o8 = {};
  if (col < EMBED) {
    const float* src = r < 584  ? Wq + (size_t)r * EMBED
                     : r < 1168 ? Wk + (size_t)(r - 584) * EMBED
                     : r < 1752 ? Wv + (size_t)(r - 1168) * EMBED
                                : Wo + (size_t)(r - 1752) * EMBED;
    const float4* s4 = (const float4*)(src + col);
    float4 f0 = s4[0], f1 = s4[1];
    o8[0] = (__bf16)f0.x; o8[1] = (__bf16)f0.y; o8[2] = (__bf16)f0.z; o8[3] = (__bf16)f0.w;
    o8[4] = (__bf16)f1.x; o8[5] = (__bf16)f1.y; o8[6] = (__bf16)f1.z; o8[7] = (__bf16)f1.w;
  }
  *(bf16x8*)(out + (size_t)r * KP + col) = o8;
}

// ---------------- QKV projection GEMM: C = A[M,KP] * B[N,KP]^T ------------
// 2-phase double-buffered LDS prefetch: issue next tile's global_load_lds
// BEFORE ds_read+MFMA on the current tile so the __syncthreads vmcnt(0)
// drain lands after ~200 cyc of compute instead of immediately.
// 1D grid (5600 blocks) with chunked XCD swizzle: all 14 bn-blocks of a
// bm-row land on one XCD -> A-tile (155 KB) is fetched into one L2 once.
// Epilogue: Q,K -> [bh][t][80]; V -> [bh][f][200] with slim index math
// (tt%4==0 with CTX=200 => no batch rollover in r; V gets bf16x4 stores).
__global__ __launch_bounds__(256) void gemm_qkv(const __bf16* __restrict__ A,
                                                const __bf16* __restrict__ Bm,
                                                __bf16* __restrict__ Q,
                                                __bf16* __restrict__ Ko,
                                                __bf16* __restrict__ V) {
  __shared__ __bf16 As[2][4096];
  __shared__ __bf16 Bs[2][4096];
  int tid = threadIdx.x;
  // bijective chunked XCD map: 5600 = 8 * 700 exactly
  int id = blockIdx.x;
  int idp = (id & 7) * 700 + (id >> 3);
  int bm = idp / 14, bn = idp - bm * 14;   // bn fast within a chunk
  int wid = tid >> 6, lane = tid & 63;
  int wm = (wid & 1) * 64, wn = (wid >> 1) * 64;
  int lr = lane & 15, lq = lane >> 4;
  const __bf16* aB = A  + (size_t)(bm * 128 + wid * 32 + (lane >> 2)) * KP + (lane & 3) * 8;
  const __bf16* bB = Bm + (size_t)(bn * 128 + wid * 32 + (lane >> 2)) * KP + (lane & 3) * 8;
  f32x4 acc[4][4] = {};
  // prologue: stage kt=0 into buffer 0
  gld_lds16(As[0] + wid * 1024,       aB);
  gld_lds16(As[0] + wid * 1024 + 512, aB + 16 * KP);
  gld_lds16(Bs[0] + wid * 1024,       bB);
  gld_lds16(Bs[0] + wid * 1024 + 512, bB + 16 * KP);
  __syncthreads();
  int cur = 0;
  for (int kt = 0; kt < 19; ++kt) {
    if (kt < 18) {                       // prefetch next tile into other buf
      int k0 = (kt + 1) * 32;
      gld_lds16(As[cur ^ 1] + wid * 1024,       aB + k0);
      gld_lds16(As[cur ^ 1] + wid * 1024 + 512, aB + 16 * KP + k0);
      gld_lds16(Bs[cur ^ 1] + wid * 1024,       bB + k0);
      gld_lds16(Bs[cur ^ 1] + wid * 1024 + 512, bB + 16 * KP + k0);
    }
    bf16x8 af[4], bfr[4];
#pragma unroll
    for (int i = 0; i < 4; ++i)
      af[i] = *(const bf16x8*)&As[cur][(wm + i * 16 + lr) * 32 + lq * 8];
#pragma unroll
    for (int j = 0; j < 4; ++j)
      bfr[j] = *(const bf16x8*)&Bs[cur][(wn + j * 16 + lr) * 32 + lq * 8];
#pragma unroll
    for (int i = 0; i < 4; ++i)
#pragma unroll
      for (int j = 0; j < 4; ++j)
        acc[i][j] = __builtin_amdgcn_mfma_f32_16x16x32_bf16(af[i], bfr[j], acc[i][j], 0, 0, 0);
    if (kt < 18) __syncthreads();        // drains prefetch + guards buf reuse
    cur ^= 1;
  }
  // ---- epilogue: slim index math ----
  // Q idx = bb*128000 + hh*16000 + tt*80 + f
  // V idx = bb*128000 + hh*16000 + f*200 + tt   (r-contiguous!)
  int whichj[4], ojv[4];
  __bf16* Pj[4];
  bool okj[4];
#pragma unroll
  for (int j = 0; j < 4; ++j) {
    int n = bn * 128 + wn + j * 16 + lr;
    okj[j] = (n < NQKV);
    int nn = okj[j] ? n : 0;
    int which = nn / EMBED;
    int rem = nn - which * EMBED;
    int hh = rem / HS;
    int f = rem - hh * HS;
    whichj[j] = which;
    ojv[j] = (which == 2) ? (hh * 16000 + f * 200) : (hh * 16000 + f);
    Pj[j] = (which == 0) ? Q : (which == 1) ? Ko : V;
  }
#pragma unroll
  for (int i = 0; i < 4; ++i) {
    int m0 = bm * 128 + wm + i * 16 + lq * 4;  // multiple of 4
    int bb = m0 / CTX;
    int tt = m0 - bb * CTX;                    // multiple of 4 -> tt+3 <= 199
    int a_qk = bb * 128000 + tt * 80;
    int a_v  = bb * 128000 + tt;
#pragma unroll
    for (int j = 0; j < 4; ++j) {
      if (!okj[j]) continue;
      if (whichj[j] == 2) {
        bf16x4 v4;
#pragma unroll
        for (int r = 0; r < 4; ++r) v4[r] = (__bf16)acc[i][j][r];
        *(bf16x4*)&Pj[j][a_v + ojv[j]] = v4;   // 8B-aligned (tt%4==0)
      } else {
        int base = a_qk + ojv[j];
#pragma unroll
        for (int r = 0; r < 4; ++r)
          Pj[j][base + r * 80] = (__bf16)acc[i][j][r];
      }
    }
  }
}

// ---------------- MFMA flash attention: one block per (b,h) ---------------
// Q,K: [bh][t][80] bf16 ; V: [bh][f][200] bf16 (transposed).
// Out: [B,T,KP] bf16 (pad cols 584..607 zeroed by h==0 blocks).
__global__ __launch_bounds__(256) void attn_kernel(const __bf16* __restrict__ q,
                                                   const __bf16* __restrict__ k,
                                                   const __bf16* __restrict__ v,
                                                   __bf16* __restrict__ o) {
  // LDS: Ks[112][104] + Vt[80][136] + Ps[4][16][136] = 62464 B
  __shared__ __align__(16) __bf16 lds[31232];
  __bf16* Ks = lds;                 // 11648 hw
  __bf16* Vt = lds + 11648;         // 10880 hw
  __bf16* Ps = lds + 22528;         //  8704 hw (4 waves x 2176)

  int tid = threadIdx.x;
  int bh = blockIdx.x;
  int b = bh >> 3, h = bh & 7;
  const __bf16* qg = q + (size_t)bh * (CTX * HSQ);
  const __bf16* kg = k + (size_t)bh * (CTX * HSQ);
  const __bf16* vg = v + (size_t)bh * (HSQ * CTX);

  // zero all LDS once (pad cols MUST be 0.0, not junk: 0*NaN=NaN)
  {
    f32x4* p = (f32x4*)lds;
    for (int i = tid; i < 3904; i += 256) p[i] = f32x4{0.f, 0.f, 0.f, 0.f};
  }
  // zero output pad columns (once per (b,t); h==0 blocks only)
  if (h == 0) {
    bf16x8 z = {};
    for (int i = tid; i < CTX * 3; i += 256) {
      int t = i / 3, seg = i - t * 3;
      *(bf16x8*)&o[((size_t)(b * CTX + t)) * KP + EMBED + seg * 8] = z;
    }
  }
  __syncthreads();

  int wid = tid >> 6, lane = tid & 63;
  int lr = lane & 15, g = lane >> 4;
  __bf16* Pw = Ps + wid * (16 * PSS);
  const int nstr = (wid == 0) ? 4 : 3;   // strips: wid, wid+4, wid+8, (12)
  const float scale = 0.04138029443264672f;  // 584^-0.5

  float ml[4][4], ll[4][4];
  f32x4 ov[4][5];
#pragma unroll
  for (int i = 0; i < 4; ++i)
#pragma unroll
    for (int r = 0; r < 4; ++r) { ml[i][r] = -1e30f; ll[i][r] = 0.f; }
#pragma unroll
  for (int i = 0; i < 4; ++i)
#pragma unroll
    for (int nt = 0; nt < 5; ++nt) ov[i][nt] = f32x4{0.f, 0.f, 0.f, 0.f};

  for (int c = 0; c < 2; ++c) {
    int key0 = c * CH;
    // ---- stage Ks [s][f] from K rows (coalesced: contiguous global) ----
    for (int idx = tid; idx < CH * 10; idx += 256) {
      int s = idx / 10, slot = idx % 10;
      int key = key0 + s;
      if (key < CTX)
        *(bf16x8*)&Ks[s * KSS + slot * 8] =
            *(const bf16x8*)&kg[(size_t)key * HSQ + slot * 8];
    }
    // ---- stage Vt [f][s] from transposed V rows ----
    for (int idx = tid; idx < HSQ * 14; idx += 256) {
      int f = idx / 14, slot = idx % 14;
      int s0 = slot * 8;
      bf16x8 vv;
      if (key0 + s0 + 7 < CTX) {
        vv = *(const bf16x8*)&vg[(size_t)f * CTX + key0 + s0];
      } else {
#pragma unroll
        for (int j = 0; j < 8; ++j)
          vv[j] = (key0 + s0 + j < CTX) ? vg[(size_t)f * CTX + key0 + s0 + j]
                                        : (__bf16)0.f;
      }
      *(bf16x8*)&Vt[f * VTS + s0] = vv;
    }
    __syncthreads();

#pragma unroll
    for (int i = 0; i < 4; ++i) {
      if (i >= nstr) break;
      int strip = wid + 4 * i;
      int row0 = strip * 16;
      // Q A-fragments: A[m=lr][kf=g*8+j + kc*32]
      bf16x8 qf[3];
      qf[0] = *(const bf16x8*)&qg[(size_t)(row0 + lr) * HSQ + g * 8];
      qf[1] = *(const bf16x8*)&qg[(size_t)(row0 + lr) * HSQ + 32 + g * 8];
      if (g < 2)
        qf[2] = *(const bf16x8*)&qg[(size_t)(row0 + lr) * HSQ + 64 + g * 8];
      else
        qf[2] = bf16x8{};
      // ---- S = Q K^T over this chunk ----
      float sc[7][4];
#pragma unroll
      for (int nt = 0; nt < 7; ++nt) {
        f32x4 acc = {};
#pragma unroll
        for (int kc = 0; kc < 3; ++kc) {
          bf16x8 kf = *(const bf16x8*)&Ks[(nt * 16 + lr) * KSS + kc * 32 + g * 8];
          acc = __builtin_amdgcn_mfma_f32_16x16x32_bf16(qf[kc], kf, acc, 0, 0, 0);
        }
        int kcol = key0 + nt * 16 + lr;
#pragma unroll
        for (int r = 0; r < 4; ++r) {
          int qrow = row0 + g * 4 + r;
          sc[nt][r] = (kcol <= qrow && kcol < CTX) ? acc[r] * scale : -1e30f;
        }
      }
      // ---- online softmax (row state; reduce across the 16 lr lanes) ----
      float mc[4];
#pragma unroll
      for (int r = 0; r < 4; ++r) {
        float m = sc[0][r];
#pragma unroll
        for (int nt = 1; nt < 7; ++nt) m = fmaxf(m, sc[nt][r]);
        mc[r] = m;
      }
#pragma unroll
      for (int off = 8; off; off >>= 1)
#pragma unroll
        for (int r = 0; r < 4; ++r)
          mc[r] = fmaxf(mc[r], __shfl_xor(mc[r], off, 64));
      float alpha[4], rs[4];
#pragma unroll
      for (int r = 0; r < 4; ++r) {
        float mnew = fmaxf(ml[i][r], mc[r]);
        alpha[r] = __expf(ml[i][r] - mnew);
        ml[i][r] = mnew;
        float s = 0.f;
#pragma unroll
        for (int nt = 0; nt < 7; ++nt) {
          sc[nt][r] = __expf(sc[nt][r] - mnew);
          s += sc[nt][r];
        }
        rs[r] = s;
      }
#pragma unroll
      for (int off = 8; off; off >>= 1)
#pragma unroll
        for (int r = 0; r < 4; ++r) rs[r] += __shfl_xor(rs[r], off, 64);
#pragma unroll
      for (int r = 0; r < 4; ++r) ll[i][r] = ll[i][r] * alpha[r] + rs[r];
#pragma unroll
      for (int nt = 0; nt < 5; ++nt)
#pragma unroll
        for (int r = 0; r < 4; ++r) ov[i][nt][r] *= alpha[r];
      // ---- P -> per-wave LDS (C-layout -> A-layout round trip) ----
#pragma unroll
      for (int nt = 0; nt < 7; ++nt)
#pragma unroll
        for (int r = 0; r < 4; ++r)
          Pw[(g * 4 + r) * PSS + nt * 16 + lr] = (__bf16)sc[nt][r];
      // ---- O += P V ----
#pragma unroll
      for (int kc = 0; kc < 4; ++kc) {
        bf16x8 pf = *(const bf16x8*)&Pw[lr * PSS + kc * 32 + g * 8];
#pragma unroll
        for (int nt = 0; nt < 5; ++nt) {
          bf16x8 vf = *(const bf16x8*)&Vt[(nt * 16 + lr) * VTS + kc * 32 + g * 8];
          ov[i][nt] = __builtin_amdgcn_mfma_f32_16x16x32_bf16(pf, vf, ov[i][nt], 0, 0, 0);
        }
      }
    }
    __syncthreads();
  }
  // ---- finalize: O / l, store to [B,T,KP] head-concat ----
#pragma unroll
  for (int i = 0; i < 4; ++i) {
    if (i >= nstr) break;
    int strip = wid + 4 * i;
    float inv[4];
#pragma unroll
    for (int r = 0; r < 4; ++r) inv[r] = 1.0f / ll[i][r];
#pragma unroll
    for (int nt = 0; nt < 5; ++nt) {
      int f = nt * 16 + lr;
      if (f < HS) {
#pragma unroll
        for (int r = 0; r < 4; ++r) {
          int t = strip * 16 + g * 4 + r;
          if (t < CTX)
            o[((size_t)(b * CTX + t)) * KP + h * HS + f] =
                (__bf16)(ov[i][nt][r] * inv[r]);
        }
      }
    }
  }
}

// ---------------- output projection GEMM + bias, fp32 out -----------------
// Same 2-phase prefetch loop; 1D grid 2000 = 8 * 250, chunked XCD swizzle.
__global__ __launch_bounds__(256) void gemm_out(const __bf16* __restrict__ A,
                                                const __bf16* __restrict__ Bm,
                                                const float* __restrict__ bias,
                                                float* __restrict__ C) {
  constexpr int N = EMBED;
  __shared__ __bf16 As[2][4096];
  __shared__ __bf16 Bs[2][4096];
  int tid = threadIdx.x;
  int id = blockIdx.x;
  int idp = (id & 7) * 250 + (id >> 3);
  int bm = idp / 5, bn = idp - bm * 5;
  int wid = tid >> 6, lane = tid & 63;
  int wm = (wid & 1) * 64, wn = (wid >> 1) * 64;
  int lr = lane & 15, lq = lane >> 4;
  const __bf16* aB = A  + (size_t)(bm * 128 + wid * 32 + (lane >> 2)) * KP + (lane & 3) * 8;
  const __bf16* bB = Bm + (size_t)(bn * 128 + wid * 32 + (lane >> 2)) * KP + (lane & 3) * 8;
  f32x4 acc[4][4] = {};
  gld_lds16(As[0] + wid * 1024,       aB);
  gld_lds16(As[0] + wid * 1024 + 512, aB + 16 * KP);
  gld_lds16(Bs[0] + wid * 1024,       bB);
  gld_lds16(Bs[0] + wid * 1024 + 512, bB + 16 * KP);
  __syncthreads();
  int cur = 0;
  for (int kt = 0; kt < 19; ++kt) {
    if (kt < 18) {
      int k0 = (kt + 1) * 32;
      gld_lds16(As[cur ^ 1] + wid * 1024,       aB + k0);
      gld_lds16(As[cur ^ 1] + wid * 1024 + 512, aB + 16 * KP + k0);
      gld_lds16(Bs[cur ^ 1] + wid * 1024,       bB + k0);
      gld_lds16(Bs[cur ^ 1] + wid * 1024 + 512, bB + 16 * KP + k0);
    }
    bf16x8 af[4], bfr[4];
#pragma unroll
    for (int i = 0; i < 4; ++i)
      af[i] = *(const bf16x8*)&As[cur][(wm + i * 16 + lr) * 32 + lq * 8];
#pragma unroll
    for (int j = 0; j < 4; ++j)
      bfr[j] = *(const bf16x8*)&Bs[cur][(wn + j * 16 + lr) * 32 + lq * 8];
#pragma unroll
    for (int i = 0; i < 4; ++i)
#pragma unroll
      for (int j = 0; j < 4; ++j)
        acc[i][j] = __builtin_amdgcn_mfma_f32_16x16x32_bf16(af[i], bfr[j], acc[i][j], 0, 0, 0);
    if (kt < 18) __syncthreads();
    cur ^= 1;
  }
#pragma unroll
  for (int i = 0; i < 4; ++i) {
    int m = bm * 128 + wm + i * 16 + lq * 4;
#pragma unroll
    for (int j = 0; j < 4; ++j) {
      int n = bn * 128 + wn + j * 16 + lr;
      if (n < N) {
        float bval = bias[n];
#pragma unroll
        for (int r = 0; r < 4; ++r)
          C[(size_t)(m + r) * N + n] = acc[i][j][r] + bval;
      }
    }
  }
}

extern "C" void kernel_launch(void* const* d_in, const int* in_sizes, int n_in,
                              void* d_out, int out_size, void* d_ws, size_t ws_size,
                              hipStream_t stream) {
  const float* x  = (const float*)d_in[0];
  const float* Wq = (const float*)d_in[1];
  const float* Wk = (const float*)d_in[2];
  const float* Wv = (const float*)d_in[3];
  const float* Wo = (const float*)d_in[4];
  const float* bo = (const float*)d_in[5];
  float* out = (float*)d_out;

  // ws layout (bf16 elems), total 130,853,888 elems = 261.7 MB:
  //  xb   [51200*608] = 31,129,600  (reused as ab after gemm_qkv)
  //  wcat [2336*608]  =  1,420,288
  //  qb   [2048*200*80] = 32,768,000
  //  kb   same
  //  vb   same (transposed: [bh][f][t])
  __bf16* xb   = (__bf16*)d_ws;
  __bf16* wcat = xb + 31129600ULL;
  __bf16* qb   = wcat + 1420288ULL;
  __bf16* kb   = qb + 32768000ULL;
  __bf16* vb   = kb + 32768000ULL;
  __bf16* ab   = xb;  // alias: xb dead after gemm_qkv

  cvt_x<<<15200, 256, 0, stream>>>(x, xb);
  pack_w<<<694, 256, 0, stream>>>(Wq, Wk, Wv, Wo, wcat);
  gemm_qkv<<<5600, 256, 0, stream>>>(xb, wcat, qb, kb, vb);
  attn_kernel<<<2048, 256, 0, stream>>>(qb, kb, vb, ab);
  gemm_out<<<2000, 256, 0, stream>>>(ab, wcat + 1752ULL * KP, bo, out);
}

// Round 2
// 684.048 us; speedup vs baseline: 1.0896x; 1.0653x over previous
//
#include <hip/hip_runtime.h>

typedef __bf16 bf16x8 __attribute__((ext_vector_type(8)));
typedef __bf16 bf16x4 __attribute__((ext_vector_type(4)));
typedef float f32x4 __attribute__((ext_vector_type(4)));

#define EMBED 584
#define KP 608      // K padded to 19*32 (zero-filled cols 584..607)
#define HEADS 8
#define HS 73
#define HSQ 80      // padded head size in q/k storage (16B-aligned rows)
#define CTX 200
#define NBATCH 256
#define MROWS 51200 // NBATCH*CTX
#define NQKV 1752   // 3*EMBED

// attention P-scratch stride (halfwords): 14 tiles*16 = 224 used + 8 pad.
// 232 hw = 464 B = 116 dwords; 116 mod 32 = 20 -> only lr/lr+8 share a bank
// on ds_read_b128 (2-way, free per m136).
#define PSS 232

// async global->LDS 16B copy: LDS dest is wave-uniform base + lane*16
__device__ __forceinline__ void gld_lds16(__bf16* lds, const __bf16* g) {
  __builtin_amdgcn_global_load_lds(
      (const __attribute__((address_space(1))) void*)g,
      (__attribute__((address_space(3))) void*)lds, 16, 0, 0);
}

// ---- fp32 -> bf16 convert x into padded [51200][608], 8 elems/thread ----
__global__ __launch_bounds__(256) void cvt_x(const float* __restrict__ x,
                                             __bf16* __restrict__ out) {
  int i = blockIdx.x * 256 + threadIdx.x;   // 15200*256 = 3,891,200 exact
  int r = i / 76, slot = i - r * 76;
  int col = slot * 8;
  bf16x8 o8 = {};
  if (col < EMBED) {
    const float4* s4 = (const float4*)(x + (size_t)r * EMBED + col);
    float4 f0 = s4[0], f1 = s4[1];
    o8[0] = (__bf16)f0.x; o8[1] = (__bf16)f0.y; o8[2] = (__bf16)f0.z; o8[3] = (__bf16)f0.w;
    o8[4] = (__bf16)f1.x; o8[5] = (__bf16)f1.y; o8[6] = (__bf16)f1.z; o8[7] = (__bf16)f1.w;
  }
  *(bf16x8*)(out + (size_t)r * KP + col) = o8;
}

// ---- pack Wq|Wk|Wv|Wo -> bf16 [2336][608] (zero pad cols) ----
__global__ __launch_bounds__(256) void pack_w(const float* __restrict__ Wq,
                                              const float* __restrict__ Wk,
                                              const float* __restrict__ Wv,
                                              const float* __restrict__ Wo,
                                              __bf16* __restrict__ out) {
  int i = blockIdx.x * 256 + threadIdx.x;
  if (i >= 2336 * 76) return;
  int r = i / 76, slot = i - r * 76;
  int col = slot * 8;
  bf16x8 o8 = {};
  if (col < EMBED) {
    const float* src = r < 584  ? Wq + (size_t)r * EMBED
                     : r < 1168 ? Wk + (size_t)(r - 584) * EMBED
                     : r < 1752 ? Wv + (size_t)(r - 1168) * EMBED
                                : Wo + (size_t)(r - 1752) * EMBED;
    const float4* s4 = (const float4*)(src + col);
    float4 f0 = s4[0], f1 = s4[1];
    o8[0] = (__bf16)f0.x; o8[1] = (__bf16)f0.y; o8[2] = (__bf16)f0.z; o8[3] = (__bf16)f0.w;
    o8[4] = (__bf16)f1.x; o8[5] = (__bf16)f1.y; o8[6] = (__bf16)f1.z; o8[7] = (__bf16)f1.w;
  }
  *(bf16x8*)(out + (size_t)r * KP + col) = o8;
}

// ---- zero the pad lanes attention reads directly from global ----
// q/k rows: cols 72..79 (col 72 later overwritten by gemm_qkv -> run first).
// v: pad rows f=73..79 (f=72's 32-col overread lands in row 73 -> must be 0).
__global__ __launch_bounds__(256) void zero_pads(__bf16* __restrict__ qb,
                                                 __bf16* __restrict__ kb,
                                                 __bf16* __restrict__ vb) {
  int bh = blockIdx.x;
  bf16x8 z = {};
  __bf16* qp = qb + (size_t)bh * 16000;
  __bf16* kp = kb + (size_t)bh * 16000;
  __bf16* vp = vb + (size_t)bh * 16000;
  for (int i = threadIdx.x; i < 575; i += 256) {
    if (i < 200)      *(bf16x8*)&qp[i * 80 + 72] = z;
    else if (i < 400) *(bf16x8*)&kp[(i - 200) * 80 + 72] = z;
    else              *(bf16x8*)&vp[14600 + (i - 400) * 8] = z;
  }
}

// ---------------- QKV projection GEMM: C = A[M,KP] * B[N,KP]^T ------------
// 2-phase double-buffered LDS prefetch; chunked XCD swizzle (5600 = 8*700).
__global__ __launch_bounds__(256) void gemm_qkv(const __bf16* __restrict__ A,
                                                const __bf16* __restrict__ Bm,
                                                __bf16* __restrict__ Q,
                                                __bf16* __restrict__ Ko,
                                                __bf16* __restrict__ V) {
  __shared__ __bf16 As[2][4096];
  __shared__ __bf16 Bs[2][4096];
  int tid = threadIdx.x;
  int id = blockIdx.x;
  int idp = (id & 7) * 700 + (id >> 3);
  int bm = idp / 14, bn = idp - bm * 14;   // bn fast within a chunk
  int wid = tid >> 6, lane = tid & 63;
  int wm = (wid & 1) * 64, wn = (wid >> 1) * 64;
  int lr = lane & 15, lq = lane >> 4;
  const __bf16* aB = A  + (size_t)(bm * 128 + wid * 32 + (lane >> 2)) * KP + (lane & 3) * 8;
  const __bf16* bB = Bm + (size_t)(bn * 128 + wid * 32 + (lane >> 2)) * KP + (lane & 3) * 8;
  f32x4 acc[4][4] = {};
  gld_lds16(As[0] + wid * 1024,       aB);
  gld_lds16(As[0] + wid * 1024 + 512, aB + 16 * KP);
  gld_lds16(Bs[0] + wid * 1024,       bB);
  gld_lds16(Bs[0] + wid * 1024 + 512, bB + 16 * KP);
  __syncthreads();
  int cur = 0;
  for (int kt = 0; kt < 19; ++kt) {
    if (kt < 18) {                       // prefetch next tile into other buf
      int k0 = (kt + 1) * 32;
      gld_lds16(As[cur ^ 1] + wid * 1024,       aB + k0);
      gld_lds16(As[cur ^ 1] + wid * 1024 + 512, aB + 16 * KP + k0);
      gld_lds16(Bs[cur ^ 1] + wid * 1024,       bB + k0);
      gld_lds16(Bs[cur ^ 1] + wid * 1024 + 512, bB + 16 * KP + k0);
    }
    bf16x8 af[4], bfr[4];
#pragma unroll
    for (int i = 0; i < 4; ++i)
      af[i] = *(const bf16x8*)&As[cur][(wm + i * 16 + lr) * 32 + lq * 8];
#pragma unroll
    for (int j = 0; j < 4; ++j)
      bfr[j] = *(const bf16x8*)&Bs[cur][(wn + j * 16 + lr) * 32 + lq * 8];
#pragma unroll
    for (int i = 0; i < 4; ++i)
#pragma unroll
      for (int j = 0; j < 4; ++j)
        acc[i][j] = __builtin_amdgcn_mfma_f32_16x16x32_bf16(af[i], bfr[j], acc[i][j], 0, 0, 0);
    if (kt < 18) __syncthreads();
    cur ^= 1;
  }
  // ---- epilogue: slim index math ----
  int whichj[4], ojv[4];
  __bf16* Pj[4];
  bool okj[4];
#pragma unroll
  for (int j = 0; j < 4; ++j) {
    int n = bn * 128 + wn + j * 16 + lr;
    okj[j] = (n < NQKV);
    int nn = okj[j] ? n : 0;
    int which = nn / EMBED;
    int rem = nn - which * EMBED;
    int hh = rem / HS;
    int f = rem - hh * HS;
    whichj[j] = which;
    ojv[j] = (which == 2) ? (hh * 16000 + f * 200) : (hh * 16000 + f);
    Pj[j] = (which == 0) ? Q : (which == 1) ? Ko : V;
  }
#pragma unroll
  for (int i = 0; i < 4; ++i) {
    int m0 = bm * 128 + wm + i * 16 + lq * 4;  // multiple of 4
    int bb = m0 / CTX;
    int tt = m0 - bb * CTX;                    // multiple of 4 -> tt+3 <= 199
    int a_qk = bb * 128000 + tt * 80;
    int a_v  = bb * 128000 + tt;
#pragma unroll
    for (int j = 0; j < 4; ++j) {
      if (!okj[j]) continue;
      if (whichj[j] == 2) {
        bf16x4 v4;
#pragma unroll
        for (int r = 0; r < 4; ++r) v4[r] = (__bf16)acc[i][j][r];
        *(bf16x4*)&Pj[j][a_v + ojv[j]] = v4;   // 8B-aligned (tt%4==0)
      } else {
        int base = a_qk + ojv[j];
#pragma unroll
        for (int r = 0; r < 4; ++r)
          Pj[j][base + r * 80] = (__bf16)acc[i][j][r];
      }
    }
  }
}

// ---------------- MFMA flash attention: one block per (b,h) ---------------
// Barrier-free, single-pass-softmax, causality-skipping.
// Q,K: [bh][t][80] bf16 ; V: [bh][f][200] bf16 (transposed).
// K/V read directly from global (L1/L2-served; ~64KB per block).
// Per wave: balanced strip sets {12,6,1}/{11,7,2}/{10,8,3}/{9,5,4,0}.
// LDS: only per-wave P round-trip (4 x 16 x PSS hw = 29,696 B).
__global__ __launch_bounds__(256, 4) void attn_kernel(const __bf16* __restrict__ q,
                                                      const __bf16* __restrict__ k,
                                                      const __bf16* __restrict__ v,
                                                      __bf16* __restrict__ o) {
  __shared__ __align__(16) __bf16 Ps[4][16 * PSS];
  int tid = threadIdx.x;
  int bh = blockIdx.x;
  int b = bh >> 3, h = bh & 7;
  const __bf16* qg = q + (size_t)bh * 16000;
  const __bf16* kg = k + (size_t)bh * 16000;
  const __bf16* vg = v + (size_t)bh * 16000;

  // zero output pad columns (once per (b,t); h==0 blocks only)
  if (h == 0) {
    bf16x8 z = {};
    for (int i = tid; i < CTX * 3; i += 256) {
      int t = i / 3, seg = i - t * 3;
      *(bf16x8*)&o[((size_t)(b * CTX + t)) * KP + EMBED + seg * 8] = z;
    }
  }

  int wid = tid >> 6, lane = tid & 63;
  int lr = lane & 15, g = lane >> 4;
  __bf16* Pw = Ps[wid];
  const float scale = 0.04138029443264672f;  // 584^-0.5

  // balanced strip map: units(s)=s+1 -> totals {22,23,24,22}
  int sl[4];
  sl[0] = 12 - wid;                   // 12,11,10,9
  sl[1] = (wid < 3) ? 6 + wid : 5;    // 6,7,8,5
  sl[2] = (wid < 3) ? 1 + wid : 4;    // 1,2,3,4
  sl[3] = (wid < 3) ? -1 : 0;         // -,-,-,0

#pragma unroll
  for (int si = 0; si < 4; ++si) {
    int s = sl[si];
    if (s < 0) continue;              // wave-uniform
    int row0 = s * 16;
    // Q A-fragments direct from global: A[m=lr][k=g*8+j + kc*32]
    bf16x8 qf[3];
    qf[0] = *(const bf16x8*)&qg[(size_t)(row0 + lr) * HSQ + g * 8];
    qf[1] = *(const bf16x8*)&qg[(size_t)(row0 + lr) * HSQ + 32 + g * 8];
    qf[2] = (g < 2) ? *(const bf16x8*)&qg[(size_t)(row0 + lr) * HSQ + 64 + g * 8]
                    : bf16x8{};
    // ---- S = Q K^T, keys 0 .. 16(s+1)-1 only (causal skip) ----
    float sc[13][4];
#pragma unroll
    for (int nt = 0; nt < 13; ++nt) {
      if (nt > s) continue;           // wave-uniform skip
      f32x4 acc = {};
#pragma unroll
      for (int kc = 0; kc < 3; ++kc) {
        bf16x8 kf = *(const bf16x8*)&kg[(size_t)(nt * 16 + lr) * HSQ + kc * 32 + g * 8];
        acc = __builtin_amdgcn_mfma_f32_16x16x32_bf16(qf[kc], kf, acc, 0, 0, 0);
      }
#pragma unroll
      for (int r = 0; r < 4; ++r) {
        float val = acc[r] * scale;
        if (nt == s && lr > g * 4 + r) val = -1e30f;   // diagonal tile mask
        if (nt * 16 + lr >= CTX) val = -1e30f;         // keys beyond CTX
        sc[nt][r] = val;
      }
    }
    // ---- exact one-shot softmax (reduce across the 16 lr lanes) ----
    float mr[4], rs[4];
#pragma unroll
    for (int r = 0; r < 4; ++r) {
      float m = -1e30f;
#pragma unroll
      for (int nt = 0; nt < 13; ++nt)
        if (nt <= s) m = fmaxf(m, sc[nt][r]);
      mr[r] = m;
    }
#pragma unroll
    for (int off = 8; off; off >>= 1)
#pragma unroll
      for (int r = 0; r < 4; ++r)
        mr[r] = fmaxf(mr[r], __shfl_xor(mr[r], off, 64));
#pragma unroll
    for (int r = 0; r < 4; ++r) {
      float ssum = 0.f;
#pragma unroll
      for (int nt = 0; nt < 13; ++nt) {
        if (nt > s) continue;
        sc[nt][r] = __expf(sc[nt][r] - mr[r]);
        ssum += sc[nt][r];
      }
      rs[r] = ssum;
    }
#pragma unroll
    for (int off = 8; off; off >>= 1)
#pragma unroll
      for (int r = 0; r < 4; ++r) rs[r] += __shfl_xor(rs[r], off, 64);
    // ---- P -> per-wave LDS (C-layout -> A-layout); zero odd tail tile ----
#pragma unroll
    for (int nt = 0; nt < 13; ++nt) {
      if (nt > s) continue;
#pragma unroll
      for (int r = 0; r < 4; ++r)
        Pw[(g * 4 + r) * PSS + nt * 16 + lr] = (__bf16)sc[nt][r];
    }
    if ((s & 1) == 0) {
#pragma unroll
      for (int r = 0; r < 4; ++r)
        Pw[(g * 4 + r) * PSS + (s + 1) * 16 + lr] = (__bf16)0.f;
    }
    // ---- O = P V (V direct from global) ----
    f32x4 ov[5];
#pragma unroll
    for (int nt = 0; nt < 5; ++nt) ov[nt] = f32x4{0.f, 0.f, 0.f, 0.f};
#pragma unroll
    for (int kc = 0; kc < 7; ++kc) {
      if (kc > s / 2) continue;       // only key tiles with nonzero P
      bf16x8 pf = *(const bf16x8*)&Pw[lr * PSS + kc * 32 + g * 8];
#pragma unroll
      for (int nt = 0; nt < 5; ++nt) {
        bf16x8 vf = *(const bf16x8*)&vg[(size_t)(nt * 16 + lr) * CTX + kc * 32 + g * 8];
        ov[nt] = __builtin_amdgcn_mfma_f32_16x16x32_bf16(pf, vf, ov[nt], 0, 0, 0);
      }
    }
    // ---- store O / l ----
    float inv[4];
#pragma unroll
    for (int r = 0; r < 4; ++r) inv[r] = 1.0f / rs[r];
#pragma unroll
    for (int nt = 0; nt < 5; ++nt) {
      int f = nt * 16 + lr;
      if (f < HS) {
#pragma unroll
        for (int r = 0; r < 4; ++r) {
          int t = row0 + g * 4 + r;
          if (t < CTX)
            o[((size_t)(b * CTX + t)) * KP + h * HS + f] =
                (__bf16)(ov[nt][r] * inv[r]);
        }
      }
    }
  }
}

// ---------------- output projection GEMM + bias, fp32 out -----------------
__global__ __launch_bounds__(256) void gemm_out(const __bf16* __restrict__ A,
                                                const __bf16* __restrict__ Bm,
                                                const float* __restrict__ bias,
                                                float* __restrict__ C) {
  constexpr int N = EMBED;
  __shared__ __bf16 As[2][4096];
  __shared__ __bf16 Bs[2][4096];
  int tid = threadIdx.x;
  int id = blockIdx.x;
  int idp = (id & 7) * 250 + (id >> 3);
  int bm = idp / 5, bn = idp - bm * 5;
  int wid = tid >> 6, lane = tid & 63;
  int wm = (wid & 1) * 64, wn = (wid >> 1) * 64;
  int lr = lane & 15, lq = lane >> 4;
  const __bf16* aB = A  + (size_t)(bm * 128 + wid * 32 + (lane >> 2)) * KP + (lane & 3) * 8;
  const __bf16* bB = Bm + (size_t)(bn * 128 + wid * 32 + (lane >> 2)) * KP + (lane & 3) * 8;
  f32x4 acc[4][4] = {};
  gld_lds16(As[0] + wid * 1024,       aB);
  gld_lds16(As[0] + wid * 1024 + 512, aB + 16 * KP);
  gld_lds16(Bs[0] + wid * 1024,       bB);
  gld_lds16(Bs[0] + wid * 1024 + 512, bB + 16 * KP);
  __syncthreads();
  int cur = 0;
  for (int kt = 0; kt < 19; ++kt) {
    if (kt < 18) {
      int k0 = (kt + 1) * 32;
      gld_lds16(As[cur ^ 1] + wid * 1024,       aB + k0);
      gld_lds16(As[cur ^ 1] + wid * 1024 + 512, aB + 16 * KP + k0);
      gld_lds16(Bs[cur ^ 1] + wid * 1024,       bB + k0);
      gld_lds16(Bs[cur ^ 1] + wid * 1024 + 512, bB + 16 * KP + k0);
    }
    bf16x8 af[4], bfr[4];
#pragma unroll
    for (int i = 0; i < 4; ++i)
      af[i] = *(const bf16x8*)&As[cur][(wm + i * 16 + lr) * 32 + lq * 8];
#pragma unroll
    for (int j = 0; j < 4; ++j)
      bfr[j] = *(const bf16x8*)&Bs[cur][(wn + j * 16 + lr) * 32 + lq * 8];
#pragma unroll
    for (int i = 0; i < 4; ++i)
#pragma unroll
      for (int j = 0; j < 4; ++j)
        acc[i][j] = __builtin_amdgcn_mfma_f32_16x16x32_bf16(af[i], bfr[j], acc[i][j], 0, 0, 0);
    if (kt < 18) __syncthreads();
    cur ^= 1;
  }
#pragma unroll
  for (int i = 0; i < 4; ++i) {
    int m = bm * 128 + wm + i * 16 + lq * 4;
#pragma unroll
    for (int j = 0; j < 4; ++j) {
      int n = bn * 128 + wn + j * 16 + lr;
      if (n < N) {
        float bval = bias[n];
#pragma unroll
        for (int r = 0; r < 4; ++r)
          C[(size_t)(m + r) * N + n] = acc[i][j][r] + bval;
      }
    }
  }
}

extern "C" void kernel_launch(void* const* d_in, const int* in_sizes, int n_in,
                              void* d_out, int out_size, void* d_ws, size_t ws_size,
                              hipStream_t stream) {
  const float* x  = (const float*)d_in[0];
  const float* Wq = (const float*)d_in[1];
  const float* Wk = (const float*)d_in[2];
  const float* Wv = (const float*)d_in[3];
  const float* Wo = (const float*)d_in[4];
  const float* bo = (const float*)d_in[5];
  float* out = (float*)d_out;

  // ws layout (bf16 elems), total 130,853,888 elems = 261.7 MB.
  // Order chosen so every benign overflow read (attn tail strips) lands in
  // an allocated, finite buffer: wcat | vb | qb | kb | xb(=ab, last; gemm
  // staging reads end exactly at its boundary).
  __bf16* wcat = (__bf16*)d_ws;            // [2336*608]  = 1,420,288
  __bf16* vb   = wcat + 1420288ULL;        // [bh][f][200], 32,768,000
  __bf16* qb   = vb + 32768000ULL;         // [bh][t][80],  32,768,000
  __bf16* kb   = qb + 32768000ULL;         // [bh][t][80],  32,768,000
  __bf16* xb   = kb + 32768000ULL;         // [51200][608], 31,129,600
  __bf16* ab   = xb;  // alias: xb dead after gemm_qkv

  cvt_x<<<15200, 256, 0, stream>>>(x, xb);
  pack_w<<<694, 256, 0, stream>>>(Wq, Wk, Wv, Wo, wcat);
  zero_pads<<<2048, 256, 0, stream>>>(qb, kb, vb);
  gemm_qkv<<<5600, 256, 0, stream>>>(xb, wcat, qb, kb, vb);
  attn_kernel<<<2048, 256, 0, stream>>>(qb, kb, vb, ab);
  gemm_out<<<2000, 256, 0, stream>>>(ab, wcat + 1752ULL * KP, bo, out);
}

// Round 3
// 654.140 us; speedup vs baseline: 1.1394x; 1.0457x over previous
//
#include <hip/hip_runtime.h>

typedef __bf16 bf16x8 __attribute__((ext_vector_type(8)));
typedef __bf16 bf16x4 __attribute__((ext_vector_type(4)));
typedef float f32x4 __attribute__((ext_vector_type(4)));

#define EMBED 584
#define KP 608      // K padded to 19*32 (zero-filled cols 584..607)
#define HEADS 8
#define HS 73
#define HSQ 80      // padded head size in q/k storage (16B-aligned rows)
#define CTX 200
#define NBATCH 256
#define MROWS 51200 // NBATCH*CTX
#define NQKV 1752   // 3*EMBED

// attention P-scratch stride (halfwords): 14 tiles*16 = 224 used + 8 pad.
#define PSS 232

// async global->LDS 16B copy: LDS dest is wave-uniform base + lane*16
__device__ __forceinline__ void gld_lds16(__bf16* lds, const __bf16* g) {
  __builtin_amdgcn_global_load_lds(
      (const __attribute__((address_space(1))) void*)g,
      (__attribute__((address_space(3))) void*)lds, 16, 0, 0);
}

// ---- fp32 -> bf16 convert x into padded [51200][608], 8 elems/thread ----
__global__ __launch_bounds__(256) void cvt_x(const float* __restrict__ x,
                                             __bf16* __restrict__ out) {
  int i = blockIdx.x * 256 + threadIdx.x;   // 15200*256 = 3,891,200 exact
  int r = i / 76, slot = i - r * 76;
  int col = slot * 8;
  bf16x8 o8 = {};
  if (col < EMBED) {
    const float4* s4 = (const float4*)(x + (size_t)r * EMBED + col);
    float4 f0 = s4[0], f1 = s4[1];
    o8[0] = (__bf16)f0.x; o8[1] = (__bf16)f0.y; o8[2] = (__bf16)f0.z; o8[3] = (__bf16)f0.w;
    o8[4] = (__bf16)f1.x; o8[5] = (__bf16)f1.y; o8[6] = (__bf16)f1.z; o8[7] = (__bf16)f1.w;
  }
  *(bf16x8*)(out + (size_t)r * KP + col) = o8;
}

// ---- pack Wq|Wk|Wv|Wo -> bf16 [2336][608] (zero pad cols) ----
__global__ __launch_bounds__(256) void pack_w(const float* __restrict__ Wq,
                                              const float* __restrict__ Wk,
                                              const float* __restrict__ Wv,
                                              const float* __restrict__ Wo,
                                              __bf16* __restrict__ out) {
  int i = blockIdx.x * 256 + threadIdx.x;
  if (i >= 2336 * 76) return;
  int r = i / 76, slot = i - r * 76;
  int col = slot * 8;
  bf16x8 o8 = {};
  if (col < EMBED) {
    const float* src = r < 584  ? Wq + (size_t)r * EMBED
                     : r < 1168 ? Wk + (size_t)(r - 584) * EMBED
                     : r < 1752 ? Wv + (size_t)(r - 1168) * EMBED
                                : Wo + (size_t)(r - 1752) * EMBED;
    const float4* s4 = (const float4*)(src + col);
    float4 f0 = s4[0], f1 = s4[1];
    o8[0] = (__bf16)f0.x; o8[1] = (__bf16)f0.y; o8[2] = (__bf16)f0.z; o8[3] = (__bf16)f0.w;
    o8[4] = (__bf16)f1.x; o8[5] = (__bf16)f1.y; o8[6] = (__bf16)f1.z; o8[7] = (__bf16)f1.w;
  }
  *(bf16x8*)(out + (size_t)r * KP + col) = o8;
}

// ---- zero the pad lanes attention reads directly from global ----
__global__ __launch_bounds__(256) void zero_pads(__bf16* __restrict__ qb,
                                                 __bf16* __restrict__ kb,
                                                 __bf16* __restrict__ vb) {
  int bh = blockIdx.x;
  bf16x8 z = {};
  __bf16* qp = qb + (size_t)bh * 16000;
  __bf16* kp = kb + (size_t)bh * 16000;
  __bf16* vp = vb + (size_t)bh * 16000;
  for (int i = threadIdx.x; i < 575; i += 256) {
    if (i < 200)      *(bf16x8*)&qp[i * 80 + 72] = z;
    else if (i < 400) *(bf16x8*)&kp[(i - 200) * 80 + 72] = z;
    else              *(bf16x8*)&vp[14600 + (i - 400) * 8] = z;
  }
}

// ---------------- QKV projection GEMM: C = A[M,KP] * B[N,KP]^T ------------
// 3-buffer stage-ahead-2 pipeline, counted vmcnt(4) (never 0 in loop),
// ONE s_barrier per K-step; chunked XCD swizzle (5600 = 8*700).
// Safety: a wave reaching barrier A_t has retired its t-1 ds_reads (MFMA
// consumed them), so staging tile t+2 into buffer (t+2)%3 == (t-1)%3 after
// A_t is race-free; per-wave vmcnt(4) before A_t publishes tile t.
__global__ __launch_bounds__(256) void gemm_qkv(const __bf16* __restrict__ A,
                                                const __bf16* __restrict__ Bm,
                                                __bf16* __restrict__ Q,
                                                __bf16* __restrict__ Ko,
                                                __bf16* __restrict__ V) {
  __shared__ __bf16 As[3][4096];
  __shared__ __bf16 Bs[3][4096];
  int tid = threadIdx.x;
  int id = blockIdx.x;
  int idp = (id & 7) * 700 + (id >> 3);
  int bm = idp / 14, bn = idp - bm * 14;   // bn fast within a chunk
  int wid = tid >> 6, lane = tid & 63;
  int wm = (wid & 1) * 64, wn = (wid >> 1) * 64;
  int lr = lane & 15, lq = lane >> 4;
  const __bf16* aB = A  + (size_t)(bm * 128 + wid * 32 + (lane >> 2)) * KP + (lane & 3) * 8;
  const __bf16* bB = Bm + (size_t)(bn * 128 + wid * 32 + (lane >> 2)) * KP + (lane & 3) * 8;
  f32x4 acc[4][4] = {};

#define STAGE_QKV(buf, kt)                                        \
  do {                                                            \
    int k0_ = (kt) * 32;                                          \
    gld_lds16(As[buf] + wid * 1024,       aB + k0_);              \
    gld_lds16(As[buf] + wid * 1024 + 512, aB + 16 * KP + k0_);    \
    gld_lds16(Bs[buf] + wid * 1024,       bB + k0_);              \
    gld_lds16(Bs[buf] + wid * 1024 + 512, bB + 16 * KP + k0_);    \
  } while (0)

  STAGE_QKV(0, 0);
  STAGE_QKV(1, 1);
#pragma unroll
  for (int kt = 0; kt < 19; ++kt) {
    if (kt < 18) asm volatile("s_waitcnt vmcnt(4)" ::: "memory");
    else         asm volatile("s_waitcnt vmcnt(0)" ::: "memory");
    __builtin_amdgcn_s_barrier();
    if (kt + 2 < 19) STAGE_QKV((kt + 2) % 3, kt + 2);
    const __bf16* Ac = As[kt % 3];
    const __bf16* Bc = Bs[kt % 3];
    bf16x8 af[4], bfr[4];
#pragma unroll
    for (int i = 0; i < 4; ++i)
      af[i] = *(const bf16x8*)&Ac[(wm + i * 16 + lr) * 32 + lq * 8];
#pragma unroll
    for (int j = 0; j < 4; ++j)
      bfr[j] = *(const bf16x8*)&Bc[(wn + j * 16 + lr) * 32 + lq * 8];
    __builtin_amdgcn_s_setprio(1);
#pragma unroll
    for (int i = 0; i < 4; ++i)
#pragma unroll
      for (int j = 0; j < 4; ++j)
        acc[i][j] = __builtin_amdgcn_mfma_f32_16x16x32_bf16(af[i], bfr[j], acc[i][j], 0, 0, 0);
    __builtin_amdgcn_s_setprio(0);
  }
#undef STAGE_QKV
  // ---- epilogue: slim index math ----
  int whichj[4], ojv[4];
  __bf16* Pj[4];
  bool okj[4];
#pragma unroll
  for (int j = 0; j < 4; ++j) {
    int n = bn * 128 + wn + j * 16 + lr;
    okj[j] = (n < NQKV);
    int nn = okj[j] ? n : 0;
    int which = nn / EMBED;
    int rem = nn - which * EMBED;
    int hh = rem / HS;
    int f = rem - hh * HS;
    whichj[j] = which;
    ojv[j] = (which == 2) ? (hh * 16000 + f * 200) : (hh * 16000 + f);
    Pj[j] = (which == 0) ? Q : (which == 1) ? Ko : V;
  }
#pragma unroll
  for (int i = 0; i < 4; ++i) {
    int m0 = bm * 128 + wm + i * 16 + lq * 4;  // multiple of 4
    int bb = m0 / CTX;
    int tt = m0 - bb * CTX;                    // multiple of 4 -> tt+3 <= 199
    int a_qk = bb * 128000 + tt * 80;
    int a_v  = bb * 128000 + tt;
#pragma unroll
    for (int j = 0; j < 4; ++j) {
      if (!okj[j]) continue;
      if (whichj[j] == 2) {
        bf16x4 v4;
#pragma unroll
        for (int r = 0; r < 4; ++r) v4[r] = (__bf16)acc[i][j][r];
        *(bf16x4*)&Pj[j][a_v + ojv[j]] = v4;   // 8B-aligned (tt%4==0)
      } else {
        int base = a_qk + ojv[j];
#pragma unroll
        for (int r = 0; r < 4; ++r)
          Pj[j][base + r * 80] = (__bf16)acc[i][j][r];
      }
    }
  }
}

// ---------------- MFMA flash attention: one block per (b,h) ---------------
// Barrier-free, single-pass-softmax, causality-skipping. (unchanged r2)
__global__ __launch_bounds__(256, 4) void attn_kernel(const __bf16* __restrict__ q,
                                                      const __bf16* __restrict__ k,
                                                      const __bf16* __restrict__ v,
                                                      __bf16* __restrict__ o) {
  __shared__ __align__(16) __bf16 Ps[4][16 * PSS];
  int tid = threadIdx.x;
  int bh = blockIdx.x;
  int b = bh >> 3, h = bh & 7;
  const __bf16* qg = q + (size_t)bh * 16000;
  const __bf16* kg = k + (size_t)bh * 16000;
  const __bf16* vg = v + (size_t)bh * 16000;

  if (h == 0) {
    bf16x8 z = {};
    for (int i = tid; i < CTX * 3; i += 256) {
      int t = i / 3, seg = i - t * 3;
      *(bf16x8*)&o[((size_t)(b * CTX + t)) * KP + EMBED + seg * 8] = z;
    }
  }

  int wid = tid >> 6, lane = tid & 63;
  int lr = lane & 15, g = lane >> 4;
  __bf16* Pw = Ps[wid];
  const float scale = 0.04138029443264672f;  // 584^-0.5

  int sl[4];
  sl[0] = 12 - wid;                   // 12,11,10,9
  sl[1] = (wid < 3) ? 6 + wid : 5;    // 6,7,8,5
  sl[2] = (wid < 3) ? 1 + wid : 4;    // 1,2,3,4
  sl[3] = (wid < 3) ? -1 : 0;         // -,-,-,0

#pragma unroll
  for (int si = 0; si < 4; ++si) {
    int s = sl[si];
    if (s < 0) continue;              // wave-uniform
    int row0 = s * 16;
    bf16x8 qf[3];
    qf[0] = *(const bf16x8*)&qg[(size_t)(row0 + lr) * HSQ + g * 8];
    qf[1] = *(const bf16x8*)&qg[(size_t)(row0 + lr) * HSQ + 32 + g * 8];
    qf[2] = (g < 2) ? *(const bf16x8*)&qg[(size_t)(row0 + lr) * HSQ + 64 + g * 8]
                    : bf16x8{};
    float sc[13][4];
#pragma unroll
    for (int nt = 0; nt < 13; ++nt) {
      if (nt > s) continue;           // wave-uniform skip
      f32x4 acc = {};
#pragma unroll
      for (int kc = 0; kc < 3; ++kc) {
        bf16x8 kf = *(const bf16x8*)&kg[(size_t)(nt * 16 + lr) * HSQ + kc * 32 + g * 8];
        acc = __builtin_amdgcn_mfma_f32_16x16x32_bf16(qf[kc], kf, acc, 0, 0, 0);
      }
#pragma unroll
      for (int r = 0; r < 4; ++r) {
        float val = acc[r] * scale;
        if (nt == s && lr > g * 4 + r) val = -1e30f;   // diagonal tile mask
        if (nt * 16 + lr >= CTX) val = -1e30f;         // keys beyond CTX
        sc[nt][r] = val;
      }
    }
    float mr[4], rs[4];
#pragma unroll
    for (int r = 0; r < 4; ++r) {
      float m = -1e30f;
#pragma unroll
      for (int nt = 0; nt < 13; ++nt)
        if (nt <= s) m = fmaxf(m, sc[nt][r]);
      mr[r] = m;
    }
#pragma unroll
    for (int off = 8; off; off >>= 1)
#pragma unroll
      for (int r = 0; r < 4; ++r)
        mr[r] = fmaxf(mr[r], __shfl_xor(mr[r], off, 64));
#pragma unroll
    for (int r = 0; r < 4; ++r) {
      float ssum = 0.f;
#pragma unroll
      for (int nt = 0; nt < 13; ++nt) {
        if (nt > s) continue;
        sc[nt][r] = __expf(sc[nt][r] - mr[r]);
        ssum += sc[nt][r];
      }
      rs[r] = ssum;
    }
#pragma unroll
    for (int off = 8; off; off >>= 1)
#pragma unroll
      for (int r = 0; r < 4; ++r) rs[r] += __shfl_xor(rs[r], off, 64);
#pragma unroll
    for (int nt = 0; nt < 13; ++nt) {
      if (nt > s) continue;
#pragma unroll
      for (int r = 0; r < 4; ++r)
        Pw[(g * 4 + r) * PSS + nt * 16 + lr] = (__bf16)sc[nt][r];
    }
    if ((s & 1) == 0) {
#pragma unroll
      for (int r = 0; r < 4; ++r)
        Pw[(g * 4 + r) * PSS + (s + 1) * 16 + lr] = (__bf16)0.f;
    }
    f32x4 ov[5];
#pragma unroll
    for (int nt = 0; nt < 5; ++nt) ov[nt] = f32x4{0.f, 0.f, 0.f, 0.f};
#pragma unroll
    for (int kc = 0; kc < 7; ++kc) {
      if (kc > s / 2) continue;       // only key tiles with nonzero P
      bf16x8 pf = *(const bf16x8*)&Pw[lr * PSS + kc * 32 + g * 8];
#pragma unroll
      for (int nt = 0; nt < 5; ++nt) {
        bf16x8 vf = *(const bf16x8*)&vg[(size_t)(nt * 16 + lr) * CTX + kc * 32 + g * 8];
        ov[nt] = __builtin_amdgcn_mfma_f32_16x16x32_bf16(pf, vf, ov[nt], 0, 0, 0);
      }
    }
    float inv[4];
#pragma unroll
    for (int r = 0; r < 4; ++r) inv[r] = 1.0f / rs[r];
#pragma unroll
    for (int nt = 0; nt < 5; ++nt) {
      int f = nt * 16 + lr;
      if (f < HS) {
#pragma unroll
        for (int r = 0; r < 4; ++r) {
          int t = row0 + g * 4 + r;
          if (t < CTX)
            o[((size_t)(b * CTX + t)) * KP + h * HS + f] =
                (__bf16)(ov[nt][r] * inv[r]);
        }
      }
    }
  }
}

// ---------------- output projection GEMM + bias, fp32 out -----------------
// Same 3-buffer counted-vmcnt pipeline; 1D grid 2000 = 8*250, XCD swizzle.
__global__ __launch_bounds__(256) void gemm_out(const __bf16* __restrict__ A,
                                                const __bf16* __restrict__ Bm,
                                                const float* __restrict__ bias,
                                                float* __restrict__ C) {
  constexpr int N = EMBED;
  __shared__ __bf16 As[3][4096];
  __shared__ __bf16 Bs[3][4096];
  int tid = threadIdx.x;
  int id = blockIdx.x;
  int idp = (id & 7) * 250 + (id >> 3);
  int bm = idp / 5, bn = idp - bm * 5;
  int wid = tid >> 6, lane = tid & 63;
  int wm = (wid & 1) * 64, wn = (wid >> 1) * 64;
  int lr = lane & 15, lq = lane >> 4;
  const __bf16* aB = A  + (size_t)(bm * 128 + wid * 32 + (lane >> 2)) * KP + (lane & 3) * 8;
  const __bf16* bB = Bm + (size_t)(bn * 128 + wid * 32 + (lane >> 2)) * KP + (lane & 3) * 8;
  f32x4 acc[4][4] = {};

#define STAGE_OUT(buf, kt)                                        \
  do {                                                            \
    int k0_ = (kt) * 32;                                          \
    gld_lds16(As[buf] + wid * 1024,       aB + k0_);              \
    gld_lds16(As[buf] + wid * 1024 + 512, aB + 16 * KP + k0_);    \
    gld_lds16(Bs[buf] + wid * 1024,       bB + k0_);              \
    gld_lds16(Bs[buf] + wid * 1024 + 512, bB + 16 * KP + k0_);    \
  } while (0)

  STAGE_OUT(0, 0);
  STAGE_OUT(1, 1);
#pragma unroll
  for (int kt = 0; kt < 19; ++kt) {
    if (kt < 18) asm volatile("s_waitcnt vmcnt(4)" ::: "memory");
    else         asm volatile("s_waitcnt vmcnt(0)" ::: "memory");
    __builtin_amdgcn_s_barrier();
    if (kt + 2 < 19) STAGE_OUT((kt + 2) % 3, kt + 2);
    const __bf16* Ac = As[kt % 3];
    const __bf16* Bc = Bs[kt % 3];
    bf16x8 af[4], bfr[4];
#pragma unroll
    for (int i = 0; i < 4; ++i)
      af[i] = *(const bf16x8*)&Ac[(wm + i * 16 + lr) * 32 + lq * 8];
#pragma unroll
    for (int j = 0; j < 4; ++j)
      bfr[j] = *(const bf16x8*)&Bc[(wn + j * 16 + lr) * 32 + lq * 8];
    __builtin_amdgcn_s_setprio(1);
#pragma unroll
    for (int i = 0; i < 4; ++i)
#pragma unroll
      for (int j = 0; j < 4; ++j)
        acc[i][j] = __builtin_amdgcn_mfma_f32_16x16x32_bf16(af[i], bfr[j], acc[i][j], 0, 0, 0);
    __builtin_amdgcn_s_setprio(0);
  }
#undef STAGE_OUT
#pragma unroll
  for (int i = 0; i < 4; ++i) {
    int m = bm * 128 + wm + i * 16 + lq * 4;
#pragma unroll
    for (int j = 0; j < 4; ++j) {
      int n = bn * 128 + wn + j * 16 + lr;
      if (n < N) {
        float bval = bias[n];
#pragma unroll
        for (int r = 0; r < 4; ++r)
          C[(size_t)(m + r) * N + n] = acc[i][j][r] + bval;
      }
    }
  }
}

extern "C" void kernel_launch(void* const* d_in, const int* in_sizes, int n_in,
                              void* d_out, int out_size, void* d_ws, size_t ws_size,
                              hipStream_t stream) {
  const float* x  = (const float*)d_in[0];
  const float* Wq = (const float*)d_in[1];
  const float* Wk = (const float*)d_in[2];
  const float* Wv = (const float*)d_in[3];
  const float* Wo = (const float*)d_in[4];
  const float* bo = (const float*)d_in[5];
  float* out = (float*)d_out;

  // ws layout (bf16 elems), total 130,853,888 elems = 261.7 MB.
  __bf16* wcat = (__bf16*)d_ws;            // [2336*608]  = 1,420,288
  __bf16* vb   = wcat + 1420288ULL;        // [bh][f][200], 32,768,000
  __bf16* qb   = vb + 32768000ULL;         // [bh][t][80],  32,768,000
  __bf16* kb   = qb + 32768000ULL;         // [bh][t][80],  32,768,000
  __bf16* xb   = kb + 32768000ULL;         // [51200][608], 31,129,600
  __bf16* ab   = xb;  // alias: xb dead after gemm_qkv

  cvt_x<<<15200, 256, 0, stream>>>(x, xb);
  pack_w<<<694, 256, 0, stream>>>(Wq, Wk, Wv, Wo, wcat);
  zero_pads<<<2048, 256, 0, stream>>>(qb, kb, vb);
  gemm_qkv<<<5600, 256, 0, stream>>>(xb, wcat, qb, kb, vb);
  attn_kernel<<<2048, 256, 0, stream>>>(qb, kb, vb, ab);
  gemm_out<<<2000, 256, 0, stream>>>(ab, wcat + 1752ULL * KP, bo, out);
}

// Round 4
// 630.928 us; speedup vs baseline: 1.1813x; 1.0368x over previous
//
#include <hip/hip_runtime.h>

typedef __bf16 bf16x8 __attribute__((ext_vector_type(8)));
typedef __bf16 bf16x4 __attribute__((ext_vector_type(4)));
typedef float f32x4 __attribute__((ext_vector_type(4)));

#define EMBED 584
#define KP 608      // K padded to 19*32 (zero-filled cols 584..607)
#define HEADS 8
#define HS 73
#define HSQ 80      // padded head size in q/k storage (16B-aligned rows)
#define CTX 200
#define NBATCH 256
#define MROWS 51200 // NBATCH*CTX
#define NQKV 1752   // 3*EMBED

// attention P-scratch stride (halfwords): 14 tiles*16 = 224 used + 8 pad.
#define PSS 232

// async global->LDS 16B copy: LDS dest is wave-uniform base + lane*16
__device__ __forceinline__ void gld_lds16(__bf16* lds, const __bf16* g) {
  __builtin_amdgcn_global_load_lds(
      (const __attribute__((address_space(1))) void*)g,
      (__attribute__((address_space(3))) void*)lds, 16, 0, 0);
}

// ---- fp32 -> bf16 convert x into padded [51200][608], 8 elems/thread ----
__global__ __launch_bounds__(256) void cvt_x(const float* __restrict__ x,
                                             __bf16* __restrict__ out) {
  int i = blockIdx.x * 256 + threadIdx.x;   // 15200*256 = 3,891,200 exact
  int r = i / 76, slot = i - r * 76;
  int col = slot * 8;
  bf16x8 o8 = {};
  if (col < EMBED) {
    const float4* s4 = (const float4*)(x + (size_t)r * EMBED + col);
    float4 f0 = s4[0], f1 = s4[1];
    o8[0] = (__bf16)f0.x; o8[1] = (__bf16)f0.y; o8[2] = (__bf16)f0.z; o8[3] = (__bf16)f0.w;
    o8[4] = (__bf16)f1.x; o8[5] = (__bf16)f1.y; o8[6] = (__bf16)f1.z; o8[7] = (__bf16)f1.w;
  }
  *(bf16x8*)(out + (size_t)r * KP + col) = o8;
}

// ---- pack Wq|Wk|Wv|Wo -> bf16 [2336][608] (zero pad cols) ----
__global__ __launch_bounds__(256) void pack_w(const float* __restrict__ Wq,
                                              const float* __restrict__ Wk,
                                              const float* __restrict__ Wv,
                                              const float* __restrict__ Wo,
                                              __bf16* __restrict__ out) {
  int i = blockIdx.x * 256 + threadIdx.x;
  if (i >= 2336 * 76) return;
  int r = i / 76, slot = i - r * 76;
  int col = slot * 8;
  bf16x8 o8 = {};
  if (col < EMBED) {
    const float* src = r < 584  ? Wq + (size_t)r * EMBED
                     : r < 1168 ? Wk + (size_t)(r - 584) * EMBED
                     : r < 1752 ? Wv + (size_t)(r - 1168) * EMBED
                                : Wo + (size_t)(r - 1752) * EMBED;
    const float4* s4 = (const float4*)(src + col);
    float4 f0 = s4[0], f1 = s4[1];
    o8[0] = (__bf16)f0.x; o8[1] = (__bf16)f0.y; o8[2] = (__bf16)f0.z; o8[3] = (__bf16)f0.w;
    o8[4] = (__bf16)f1.x; o8[5] = (__bf16)f1.y; o8[6] = (__bf16)f1.z; o8[7] = (__bf16)f1.w;
  }
  *(bf16x8*)(out + (size_t)r * KP + col) = o8;
}

// ---- zero the pad lanes attention reads directly from global ----
__global__ __launch_bounds__(256) void zero_pads(__bf16* __restrict__ qb,
                                                 __bf16* __restrict__ kb,
                                                 __bf16* __restrict__ vb) {
  int bh = blockIdx.x;
  bf16x8 z = {};
  __bf16* qp = qb + (size_t)bh * 16000;
  __bf16* kp = kb + (size_t)bh * 16000;
  __bf16* vp = vb + (size_t)bh * 16000;
  for (int i = threadIdx.x; i < 575; i += 256) {
    if (i < 200)      *(bf16x8*)&qp[i * 80 + 72] = z;
    else if (i < 400) *(bf16x8*)&kp[(i - 200) * 80 + 72] = z;
    else              *(bf16x8*)&vp[14600 + (i - 400) * 8] = z;
  }
}

// ---------------- QKV projection GEMM: C = A[M,KP] * B[N,KP]^T ------------
// 256x128 tile, 512 threads (8 waves, 4m x 2n of 64x64), BK=32.
// 3-buffer stage-ahead-2, counted vmcnt(3), ONE s_barrier per K-step.
// LDS 72 KB -> 2 blocks/CU = 16 waves/CU (4/SIMD) for latency hiding.
// Bank-conflict swizzle (both-sides, G21): LDS linear; global SOURCE col
// pre-swizzled c^(row&3); reads use (lq^(lr&3)) -> 8-way becomes 4-way.
// Chunked XCD swizzle: 2800 = 8*350, bn fastest for A-panel L2 reuse.
__global__ __launch_bounds__(512, 4) void gemm_qkv(const __bf16* __restrict__ A,
                                                   const __bf16* __restrict__ Bm,
                                                   __bf16* __restrict__ Q,
                                                   __bf16* __restrict__ Ko,
                                                   __bf16* __restrict__ V) {
  __shared__ __bf16 As[3][8192];   // [256][32] per buffer
  __shared__ __bf16 Bs[3][4096];   // [128][32]
  int tid = threadIdx.x;
  int id = blockIdx.x;
  int idp = (id & 7) * 350 + (id >> 3);
  int bm = idp / 14, bn = idp - bm * 14;   // bn fast within a chunk
  int wid = tid >> 6, lane = tid & 63;
  int wm = (wid & 3) * 64, wn = (wid >> 2) * 64;
  int lr = lane & 15, lq = lane >> 4;
  int sw = (((lane & 3) ^ ((lane >> 2) & 3))) * 8;   // swizzled src col
  const __bf16* aB = A  + (size_t)(bm * 256 + wid * 32 + (lane >> 2)) * KP + sw;
  const __bf16* bB = Bm + (size_t)(bn * 128 + wid * 16 + (lane >> 2)) * KP + sw;
  f32x4 acc[4][4] = {};

#define STAGE_QKV(buf, kt)                                        \
  do {                                                            \
    int k0_ = (kt) * 32;                                          \
    gld_lds16(As[buf] + wid * 1024,       aB + k0_);              \
    gld_lds16(As[buf] + wid * 1024 + 512, aB + 16 * KP + k0_);    \
    gld_lds16(Bs[buf] + wid * 512,        bB + k0_);              \
  } while (0)

  STAGE_QKV(0, 0);
  STAGE_QKV(1, 1);
  int cxr = (lq ^ (lr & 3)) * 8;   // swizzled read col for row R (R&3==lr&3)
#pragma unroll
  for (int kt = 0; kt < 19; ++kt) {
    if (kt < 18) asm volatile("s_waitcnt vmcnt(3)" ::: "memory");
    else         asm volatile("s_waitcnt vmcnt(0)" ::: "memory");
    __builtin_amdgcn_s_barrier();
    if (kt + 2 < 19) STAGE_QKV((kt + 2) % 3, kt + 2);
    const __bf16* Ac = As[kt % 3];
    const __bf16* Bc = Bs[kt % 3];
    bf16x8 af[4], bfr[4];
#pragma unroll
    for (int i = 0; i < 4; ++i)
      af[i] = *(const bf16x8*)&Ac[(wm + i * 16 + lr) * 32 + cxr];
#pragma unroll
    for (int j = 0; j < 4; ++j)
      bfr[j] = *(const bf16x8*)&Bc[(wn + j * 16 + lr) * 32 + cxr];
    __builtin_amdgcn_s_setprio(1);
#pragma unroll
    for (int i = 0; i < 4; ++i)
#pragma unroll
      for (int j = 0; j < 4; ++j)
        acc[i][j] = __builtin_amdgcn_mfma_f32_16x16x32_bf16(af[i], bfr[j], acc[i][j], 0, 0, 0);
    __builtin_amdgcn_s_setprio(0);
  }
#undef STAGE_QKV
  // ---- epilogue: slim index math ----
  int whichj[4], ojv[4];
  __bf16* Pj[4];
  bool okj[4];
#pragma unroll
  for (int j = 0; j < 4; ++j) {
    int n = bn * 128 + wn + j * 16 + lr;
    okj[j] = (n < NQKV);
    int nn = okj[j] ? n : 0;
    int which = nn / EMBED;
    int rem = nn - which * EMBED;
    int hh = rem / HS;
    int f = rem - hh * HS;
    whichj[j] = which;
    ojv[j] = (which == 2) ? (hh * 16000 + f * 200) : (hh * 16000 + f);
    Pj[j] = (which == 0) ? Q : (which == 1) ? Ko : V;
  }
#pragma unroll
  for (int i = 0; i < 4; ++i) {
    int m0 = bm * 256 + wm + i * 16 + lq * 4;  // multiple of 4
    int bb = m0 / CTX;
    int tt = m0 - bb * CTX;                    // multiple of 4 -> tt+3 <= 199
    int a_qk = bb * 128000 + tt * 80;
    int a_v  = bb * 128000 + tt;
#pragma unroll
    for (int j = 0; j < 4; ++j) {
      if (!okj[j]) continue;
      if (whichj[j] == 2) {
        bf16x4 v4;
#pragma unroll
        for (int r = 0; r < 4; ++r) v4[r] = (__bf16)acc[i][j][r];
        *(bf16x4*)&Pj[j][a_v + ojv[j]] = v4;   // 8B-aligned (tt%4==0)
      } else {
        int base = a_qk + ojv[j];
#pragma unroll
        for (int r = 0; r < 4; ++r)
          Pj[j][base + r * 80] = (__bf16)acc[i][j][r];
      }
    }
  }
}

// ---------------- MFMA flash attention: one block per (b,h) ---------------
// Barrier-free, single-pass-softmax, causality-skipping. (unchanged)
__global__ __launch_bounds__(256, 4) void attn_kernel(const __bf16* __restrict__ q,
                                                      const __bf16* __restrict__ k,
                                                      const __bf16* __restrict__ v,
                                                      __bf16* __restrict__ o) {
  __shared__ __align__(16) __bf16 Ps[4][16 * PSS];
  int tid = threadIdx.x;
  int bh = blockIdx.x;
  int b = bh >> 3, h = bh & 7;
  const __bf16* qg = q + (size_t)bh * 16000;
  const __bf16* kg = k + (size_t)bh * 16000;
  const __bf16* vg = v + (size_t)bh * 16000;

  if (h == 0) {
    bf16x8 z = {};
    for (int i = tid; i < CTX * 3; i += 256) {
      int t = i / 3, seg = i - t * 3;
      *(bf16x8*)&o[((size_t)(b * CTX + t)) * KP + EMBED + seg * 8] = z;
    }
  }

  int wid = tid >> 6, lane = tid & 63;
  int lr = lane & 15, g = lane >> 4;
  __bf16* Pw = Ps[wid];
  const float scale = 0.04138029443264672f;  // 584^-0.5

  int sl[4];
  sl[0] = 12 - wid;                   // 12,11,10,9
  sl[1] = (wid < 3) ? 6 + wid : 5;    // 6,7,8,5
  sl[2] = (wid < 3) ? 1 + wid : 4;    // 1,2,3,4
  sl[3] = (wid < 3) ? -1 : 0;         // -,-,-,0

#pragma unroll
  for (int si = 0; si < 4; ++si) {
    int s = sl[si];
    if (s < 0) continue;              // wave-uniform
    int row0 = s * 16;
    bf16x8 qf[3];
    qf[0] = *(const bf16x8*)&qg[(size_t)(row0 + lr) * HSQ + g * 8];
    qf[1] = *(const bf16x8*)&qg[(size_t)(row0 + lr) * HSQ + 32 + g * 8];
    qf[2] = (g < 2) ? *(const bf16x8*)&qg[(size_t)(row0 + lr) * HSQ + 64 + g * 8]
                    : bf16x8{};
    float sc[13][4];
#pragma unroll
    for (int nt = 0; nt < 13; ++nt) {
      if (nt > s) continue;           // wave-uniform skip
      f32x4 acc = {};
#pragma unroll
      for (int kc = 0; kc < 3; ++kc) {
        bf16x8 kf = *(const bf16x8*)&kg[(size_t)(nt * 16 + lr) * HSQ + kc * 32 + g * 8];
        acc = __builtin_amdgcn_mfma_f32_16x16x32_bf16(qf[kc], kf, acc, 0, 0, 0);
      }
#pragma unroll
      for (int r = 0; r < 4; ++r) {
        float val = acc[r] * scale;
        if (nt == s && lr > g * 4 + r) val = -1e30f;   // diagonal tile mask
        if (nt * 16 + lr >= CTX) val = -1e30f;         // keys beyond CTX
        sc[nt][r] = val;
      }
    }
    float mr[4], rs[4];
#pragma unroll
    for (int r = 0; r < 4; ++r) {
      float m = -1e30f;
#pragma unroll
      for (int nt = 0; nt < 13; ++nt)
        if (nt <= s) m = fmaxf(m, sc[nt][r]);
      mr[r] = m;
    }
#pragma unroll
    for (int off = 8; off; off >>= 1)
#pragma unroll
      for (int r = 0; r < 4; ++r)
        mr[r] = fmaxf(mr[r], __shfl_xor(mr[r], off, 64));
#pragma unroll
    for (int r = 0; r < 4; ++r) {
      float ssum = 0.f;
#pragma unroll
      for (int nt = 0; nt < 13; ++nt) {
        if (nt > s) continue;
        sc[nt][r] = __expf(sc[nt][r] - mr[r]);
        ssum += sc[nt][r];
      }
      rs[r] = ssum;
    }
#pragma unroll
    for (int off = 8; off; off >>= 1)
#pragma unroll
      for (int r = 0; r < 4; ++r) rs[r] += __shfl_xor(rs[r], off, 64);
#pragma unroll
    for (int nt = 0; nt < 13; ++nt) {
      if (nt > s) continue;
#pragma unroll
      for (int r = 0; r < 4; ++r)
        Pw[(g * 4 + r) * PSS + nt * 16 + lr] = (__bf16)sc[nt][r];
    }
    if ((s & 1) == 0) {
#pragma unroll
      for (int r = 0; r < 4; ++r)
        Pw[(g * 4 + r) * PSS + (s + 1) * 16 + lr] = (__bf16)0.f;
    }
    f32x4 ov[5];
#pragma unroll
    for (int nt = 0; nt < 5; ++nt) ov[nt] = f32x4{0.f, 0.f, 0.f, 0.f};
#pragma unroll
    for (int kc = 0; kc < 7; ++kc) {
      if (kc > s / 2) continue;       // only key tiles with nonzero P
      bf16x8 pf = *(const bf16x8*)&Pw[lr * PSS + kc * 32 + g * 8];
#pragma unroll
      for (int nt = 0; nt < 5; ++nt) {
        bf16x8 vf = *(const bf16x8*)&vg[(size_t)(nt * 16 + lr) * CTX + kc * 32 + g * 8];
        ov[nt] = __builtin_amdgcn_mfma_f32_16x16x32_bf16(pf, vf, ov[nt], 0, 0, 0);
      }
    }
    float inv[4];
#pragma unroll
    for (int r = 0; r < 4; ++r) inv[r] = 1.0f / rs[r];
#pragma unroll
    for (int nt = 0; nt < 5; ++nt) {
      int f = nt * 16 + lr;
      if (f < HS) {
#pragma unroll
        for (int r = 0; r < 4; ++r) {
          int t = row0 + g * 4 + r;
          if (t < CTX)
            o[((size_t)(b * CTX + t)) * KP + h * HS + f] =
                (__bf16)(ov[nt][r] * inv[r]);
        }
      }
    }
  }
}

// ---------------- output projection GEMM + bias, fp32 out -----------------
// Same 256x128 8-wave 3-buffer counted-vmcnt structure; 1000 = 8*125.
// B-tile bn=4 overreads 55 rows past wcat into vb: allocated, finite,
// and guarded at store (n < 584).
__global__ __launch_bounds__(512, 4) void gemm_out(const __bf16* __restrict__ A,
                                                   const __bf16* __restrict__ Bm,
                                                   const float* __restrict__ bias,
                                                   float* __restrict__ C) {
  constexpr int N = EMBED;
  __shared__ __bf16 As[3][8192];
  __shared__ __bf16 Bs[3][4096];
  int tid = threadIdx.x;
  int id = blockIdx.x;
  int idp = (id & 7) * 125 + (id >> 3);
  int bm = idp / 5, bn = idp - bm * 5;
  int wid = tid >> 6, lane = tid & 63;
  int wm = (wid & 3) * 64, wn = (wid >> 2) * 64;
  int lr = lane & 15, lq = lane >> 4;
  int sw = (((lane & 3) ^ ((lane >> 2) & 3))) * 8;
  const __bf16* aB = A  + (size_t)(bm * 256 + wid * 32 + (lane >> 2)) * KP + sw;
  const __bf16* bB = Bm + (size_t)(bn * 128 + wid * 16 + (lane >> 2)) * KP + sw;
  f32x4 acc[4][4] = {};

#define STAGE_OUT(buf, kt)                                        \
  do {                                                            \
    int k0_ = (kt) * 32;                                          \
    gld_lds16(As[buf] + wid * 1024,       aB + k0_);              \
    gld_lds16(As[buf] + wid * 1024 + 512, aB + 16 * KP + k0_);    \
    gld_lds16(Bs[buf] + wid * 512,        bB + k0_);              \
  } while (0)

  STAGE_OUT(0, 0);
  STAGE_OUT(1, 1);
  int cxr = (lq ^ (lr & 3)) * 8;
#pragma unroll
  for (int kt = 0; kt < 19; ++kt) {
    if (kt < 18) asm volatile("s_waitcnt vmcnt(3)" ::: "memory");
    else         asm volatile("s_waitcnt vmcnt(0)" ::: "memory");
    __builtin_amdgcn_s_barrier();
    if (kt + 2 < 19) STAGE_OUT((kt + 2) % 3, kt + 2);
    const __bf16* Ac = As[kt % 3];
    const __bf16* Bc = Bs[kt % 3];
    bf16x8 af[4], bfr[4];
#pragma unroll
    for (int i = 0; i < 4; ++i)
      af[i] = *(const bf16x8*)&Ac[(wm + i * 16 + lr) * 32 + cxr];
#pragma unroll
    for (int j = 0; j < 4; ++j)
      bfr[j] = *(const bf16x8*)&Bc[(wn + j * 16 + lr) * 32 + cxr];
    __builtin_amdgcn_s_setprio(1);
#pragma unroll
    for (int i = 0; i < 4; ++i)
#pragma unroll
      for (int j = 0; j < 4; ++j)
        acc[i][j] = __builtin_amdgcn_mfma_f32_16x16x32_bf16(af[i], bfr[j], acc[i][j], 0, 0, 0);
    __builtin_amdgcn_s_setprio(0);
  }
#undef STAGE_OUT
#pragma unroll
  for (int i = 0; i < 4; ++i) {
    int m = bm * 256 + wm + i * 16 + lq * 4;
#pragma unroll
    for (int j = 0; j < 4; ++j) {
      int n = bn * 128 + wn + j * 16 + lr;
      if (n < N) {
        float bval = bias[n];
#pragma unroll
        for (int r = 0; r < 4; ++r)
          C[(size_t)(m + r) * N + n] = acc[i][j][r] + bval;
      }
    }
  }
}

extern "C" void kernel_launch(void* const* d_in, const int* in_sizes, int n_in,
                              void* d_out, int out_size, void* d_ws, size_t ws_size,
                              hipStream_t stream) {
  const float* x  = (const float*)d_in[0];
  const float* Wq = (const float*)d_in[1];
  const float* Wk = (const float*)d_in[2];
  const float* Wv = (const float*)d_in[3];
  const float* Wo = (const float*)d_in[4];
  const float* bo = (const float*)d_in[5];
  float* out = (float*)d_out;

  // ws layout (bf16 elems), total 130,853,888 elems = 261.7 MB.
  __bf16* wcat = (__bf16*)d_ws;            // [2336*608]  = 1,420,288
  __bf16* vb   = wcat + 1420288ULL;        // [bh][f][200], 32,768,000
  __bf16* qb   = vb + 32768000ULL;         // [bh][t][80],  32,768,000
  __bf16* kb   = qb + 32768000ULL;         // [bh][t][80],  32,768,000
  __bf16* xb   = kb + 32768000ULL;         // [51200][608], 31,129,600
  __bf16* ab   = xb;  // alias: xb dead after gemm_qkv

  cvt_x<<<15200, 256, 0, stream>>>(x, xb);
  pack_w<<<694, 256, 0, stream>>>(Wq, Wk, Wv, Wo, wcat);
  zero_pads<<<2048, 256, 0, stream>>>(qb, kb, vb);
  gemm_qkv<<<2800, 512, 0, stream>>>(xb, wcat, qb, kb, vb);
  attn_kernel<<<2048, 256, 0, stream>>>(qb, kb, vb, ab);
  gemm_out<<<1000, 512, 0, stream>>>(ab, wcat + 1752ULL * KP, bo, out);
}